// Round 2
// baseline (1859.555 us; speedup 1.0000x reference)
//
#include <hip/hip_runtime.h>

// ---------------------------------------------------------------------------
// WindowAttention fused pipeline for MI355X (gfx950)
//   B=2048 windows, N=128 tokens, C=256, H=8 heads, hd=32
// Workspace use is ~2 MB (tables only). The bf16 concat buffer xcat lives in
// d_out (same byte size as the f32 output); the final projection runs
// in-place (all reads of a row-tile complete before its epilogue writes).
// ---------------------------------------------------------------------------

typedef __attribute__((ext_vector_type(8))) short     short8;
typedef __attribute__((ext_vector_type(8))) __bf16    bf16x8;
typedef __attribute__((ext_vector_type(4))) float     f32x4;

__device__ __forceinline__ unsigned short f2bf(float f) {
  unsigned int u = __float_as_uint(f);
  u = (u + 0x7fffu + ((u >> 16) & 1u)) >> 16;
  return (unsigned short)u;
}

__device__ __forceinline__ void gload_lds16(const void* g, void* l) {
  __builtin_amdgcn_global_load_lds((const __attribute__((address_space(1))) void*)g,
                                   (__attribute__((address_space(3))) void*)l, 16, 0, 0);
}

// ---------------- precompute kernels (~2 MB of ws) ----------------

__global__ void pos_kernel(float* __restrict__ pos_t) {
  int e = blockIdx.x * 256 + threadIdx.x;          // 32768 = 128*256
  int t = e >> 8, c = e & 255;
  int p = t & 63;                                   // tiled (1,2,1)
  const float norm = 6.28318530717958647692f / 8.000001f;  // scale/(8+1e-6)
  float yn = (float)((p >> 3) + 1) * norm;
  float xn = (float)((p & 7) + 1) * norm;
  int cc = c & 127;
  int m  = cc >> 1;
  // dim_t = 10000^(m/64); ln(10000)/64 = 0.14391156831...
  float v = ((c < 128) ? yn : xn) * __expf(-(float)m * 0.14391156831f);
  pos_t[e] = (cc & 1) ? cosf(v) : sinf(v);
}

__global__ void posw_kernel(const float* __restrict__ pos_t,
                            const float* __restrict__ Wm,
                            float* __restrict__ posW) {
  int e = blockIdx.x * 256 + threadIdx.x;          // 98304 = 128*768
  int t = e / 768, c = e - t * 768;
  const float4* pr = (const float4*)(pos_t + t * 256);
  const float4* wr = (const float4*)(Wm + (size_t)c * 256);
  float acc = 0.f;
  #pragma unroll 8
  for (int k = 0; k < 64; ++k) {
    float4 p = pr[k], w = wr[k];
    acc += p.x * w.x + p.y * w.y + p.z * w.z + p.w * w.w;
  }
  posW[e] = acc;
}

__global__ void bias_kernel(const float* __restrict__ rpb, float* __restrict__ bias_t) {
  int e = blockIdx.x * 256 + threadIdx.x;          // 131072 = 8*128*128
  int h = e >> 14, i = (e >> 7) & 127, j = e & 127;
  int di = i >> 6, hi = (i >> 3) & 7, wi = i & 7;
  int dj = j >> 6, hj = (j >> 3) & 7, wj = j & 7;
  int idx = (di - dj + 1) * 225 + (hi - hj + 7) * 15 + (wi - wj + 7);
  bias_t[e] = rpb[idx * 8 + h];
}

__global__ void wconv_kernel(const float* __restrict__ Ws, const float* __restrict__ Wm,
                             const float* __restrict__ Wp,
                             unsigned short* __restrict__ Wsb,
                             unsigned short* __restrict__ Wmb,
                             unsigned short* __restrict__ Wpb) {
  int e = blockIdx.x * 256 + threadIdx.x;          // 524288
  if (e < 196608)       Wsb[e]          = f2bf(Ws[e]);
  else if (e < 393216)  Wmb[e - 196608] = f2bf(Wm[e - 196608]);
  else                  Wpb[e - 393216] = f2bf(Wp[e - 393216]);
}

// ---------------- fused per-window QKV + attention ----------------
// One block per window b. 8 waves. LDS 158,720 B -> 1 block/CU, 2 waves/SIMD.
// Per head: Phase A computes Qs,Ks,Vs^T,Qm,Km,Vm^T (MFMA, W from L2);
// Phase B self attention (bias, 128 keys); Phase C mutual half-swap (64 keys).
// P rows are wave-private (wave w owns output rows 16w..16w+15) -> only 2
// barriers per head. xcat (bf16 [row][512]) written to d_out.

__global__ __launch_bounds__(512, 2) void fused_attn(
    const float* __restrict__ x,
    const unsigned short* __restrict__ Wsb,
    const unsigned short* __restrict__ Wmb,
    const float* __restrict__ posW,
    const float* __restrict__ bias_t,
    unsigned short* __restrict__ xcat)
{
  __shared__ unsigned short xw[128 * 256];         // 65536 B, XOR-swizzled
  __shared__ unsigned short Qs[128 * 40];          // 10240 B (cols 0..31 + pad)
  __shared__ unsigned short Ks[128 * 40];
  __shared__ unsigned short Qm[128 * 40];
  __shared__ unsigned short Km[128 * 40];
  __shared__ unsigned short VsT[32 * 136];         // 8704 B  [d][token]
  __shared__ unsigned short VmT[32 * 136];
  __shared__ unsigned short P[128 * 136];          // 34816 B

  const int b = blockIdx.x;
  const int tid = threadIdx.x, w = tid >> 6, lane = tid & 63;
  const int lr = lane & 15, lk = lane >> 4;
  const float scale = 0.17677669529663688f;        // 32^-0.5

  // ---- stage x window: f32 -> bf16, swizzled LDS ----
  {
    const float* xb = x + (size_t)b * 32768;
    #pragma unroll
    for (int i = 0; i < 8; ++i) {
      int c = tid * 8 + i;                          // chunk 0..4095 (8 elems each)
      int row = c >> 5, col = (c & 31) * 8;
      float4 a = *(const float4*)(xb + row * 256 + col);
      float4 d = *(const float4*)(xb + row * 256 + col + 4);
      short8 o;
      o[0] = (short)f2bf(a.x); o[1] = (short)f2bf(a.y);
      o[2] = (short)f2bf(a.z); o[3] = (short)f2bf(a.w);
      o[4] = (short)f2bf(d.x); o[5] = (short)f2bf(d.y);
      o[6] = (short)f2bf(d.z); o[7] = (short)f2bf(d.w);
      int addr = (row * 512 + col * 2) ^ ((row & 7) << 4);
      *(short8*)((char*)xw + addr) = o;
    }
  }

  const int m0 = w * 16;                            // this wave's output strip

  for (int h = 0; h < 8; ++h) {
    __syncthreads();   // prev head's reads done (h=0: xw staged)

    // ======== Phase A: QKV for head h ========
    // 24 units of (64 rows x 16 cols): waves 0-3 m-half 0, waves 4-7 m-half 1;
    // unit q=(w&3)*3+i -> output o=q>>1 in {Qs,Ks,Vs,Qm,Km,Vm}, ncol-tile nt=q&1.
    {
      const int mh64 = (w >> 2) * 64;
      f32x4 acc[3][4];
      #pragma unroll
      for (int i = 0; i < 3; ++i)
        #pragma unroll
        for (int mt = 0; mt < 4; ++mt) acc[i][mt] = f32x4{0.f, 0.f, 0.f, 0.f};

      int uo[3], unt[3];
      const unsigned short* wrp[3];
      #pragma unroll
      for (int i = 0; i < 3; ++i) {
        int q = (w & 3) * 3 + i;
        int o = q >> 1, nt = q & 1;
        uo[i] = o; unt[i] = nt;
        const unsigned short* WB = (o < 3) ? Wsb : Wmb;
        int o3 = (o < 3) ? o : o - 3;
        wrp[i] = WB + (size_t)(o3 * 256 + h * 32 + nt * 16 + lr) * 256 + lk * 8;
      }

      #pragma unroll
      for (int kc = 0; kc < 8; ++kc) {
        bf16x8 af[4];
        #pragma unroll
        for (int mt = 0; mt < 4; ++mt) {
          int row = mh64 + mt * 16 + lr;
          int addr = (row * 512 + kc * 64 + lk * 16) ^ ((row & 7) << 4);
          af[mt] = *(const bf16x8*)((const char*)xw + addr);
        }
        #pragma unroll
        for (int i = 0; i < 3; ++i) {
          bf16x8 bfr = *(const bf16x8*)(wrp[i] + kc * 32);
          #pragma unroll
          for (int mt = 0; mt < 4; ++mt)
            acc[i][mt] = __builtin_amdgcn_mfma_f32_16x16x32_bf16(af[mt], bfr,
                                                                 acc[i][mt], 0, 0, 0);
        }
      }

      // epilogue: C layout row=(lane>>4)*4+r, col=lane&15
      #pragma unroll
      for (int i = 0; i < 3; ++i) {
        int o = uo[i], nt = unt[i];
        #pragma unroll
        for (int mt = 0; mt < 4; ++mt)
          #pragma unroll
          for (int r = 0; r < 4; ++r) {
            int row = mh64 + mt * 16 + lk * 4 + r;   // token
            int dcol = nt * 16 + lr;                 // d within 32
            float v = acc[i][mt][r];
            if (o >= 3) v += posW[row * 768 + (o - 3) * 256 + h * 32 + dcol];
            if (o == 2)      VsT[dcol * 136 + row] = f2bf(v);
            else if (o == 5) VmT[dcol * 136 + row] = f2bf(v);
            else {
              unsigned short* Qb = (o == 0) ? Qs : (o == 1) ? Ks : (o == 3) ? Qm : Km;
              Qb[row * 40 + dcol] = f2bf(v);
            }
          }
      }
    }
    __syncthreads();   // QKV visible to all waves

    float rs[4];
    // ======== Phase B: self attention (128 keys, +bias) ========
    {
      f32x4 sc[8];
      bf16x8 qa = *(const bf16x8*)&Qs[(m0 + lr) * 40 + lk * 8];
      #pragma unroll
      for (int nf = 0; nf < 8; ++nf) {
        bf16x8 kb = *(const bf16x8*)&Ks[(nf * 16 + lr) * 40 + lk * 8];
        sc[nf] = __builtin_amdgcn_mfma_f32_16x16x32_bf16(qa, kb,
                                                         f32x4{0.f,0.f,0.f,0.f}, 0, 0, 0);
      }
      const float* bt = bias_t + (size_t)h * 16384 + (m0 + lk * 4) * 128;
      float rmax[4] = {-1e30f, -1e30f, -1e30f, -1e30f};
      float rsum[4] = {0.f, 0.f, 0.f, 0.f};
      #pragma unroll
      for (int nf = 0; nf < 8; ++nf)
        #pragma unroll
        for (int r = 0; r < 4; ++r) {
          float v = sc[nf][r] * scale + bt[r * 128 + nf * 16 + lr];
          sc[nf][r] = v;
          rmax[r] = fmaxf(rmax[r], v);
        }
      #pragma unroll
      for (int r = 0; r < 4; ++r) {
        float m = rmax[r];
        #pragma unroll
        for (int d = 1; d < 16; d <<= 1) m = fmaxf(m, __shfl_xor(m, d, 64));
        rmax[r] = m;
      }
      #pragma unroll
      for (int nf = 0; nf < 8; ++nf)
        #pragma unroll
        for (int r = 0; r < 4; ++r) {
          float p = __expf(sc[nf][r] - rmax[r]);
          rsum[r] += p;
          P[(m0 + lk * 4 + r) * 136 + nf * 16 + lr] = f2bf(p);
        }
      #pragma unroll
      for (int r = 0; r < 4; ++r) {
        float t = rsum[r];
        #pragma unroll
        for (int d = 1; d < 16; d <<= 1) t += __shfl_xor(t, d, 64);
        rs[r] = 1.f / t;
      }
      // PV (P rows are this wave's own -> no barrier; lgkmcnt dep keeps order)
      f32x4 oc[2];
      oc[0] = f32x4{0.f,0.f,0.f,0.f}; oc[1] = f32x4{0.f,0.f,0.f,0.f};
      #pragma unroll
      for (int kc = 0; kc < 4; ++kc) {
        bf16x8 pa = *(const bf16x8*)&P[(m0 + lr) * 136 + kc * 32 + lk * 8];
        #pragma unroll
        for (int nt = 0; nt < 2; ++nt) {
          bf16x8 vb = *(const bf16x8*)&VsT[(nt * 16 + lr) * 136 + kc * 32 + lk * 8];
          oc[nt] = __builtin_amdgcn_mfma_f32_16x16x32_bf16(pa, vb, oc[nt], 0, 0, 0);
        }
      }
      #pragma unroll
      for (int nt = 0; nt < 2; ++nt)
        #pragma unroll
        for (int r = 0; r < 4; ++r) {
          size_t row = (size_t)b * 128 + m0 + lk * 4 + r;
          xcat[row * 512 + 256 + h * 32 + nt * 16 + lr] = f2bf(oc[nt][r] * rs[r]);
        }
    }

    // ======== Phase C: mutual attention (half swap, 64 keys, no bias) ========
    {
      const int q0   = (w < 4) ? 64 + m0 : m0 - 64;  // q2 for rows 0..63, q1 for 64..127
      const int koff = (w < 4) ? 0 : 64;             // k1 / k2 (and v1 / v2)
      f32x4 sc2[4];
      bf16x8 qa = *(const bf16x8*)&Qm[(q0 + lr) * 40 + lk * 8];
      #pragma unroll
      for (int nf = 0; nf < 4; ++nf) {
        bf16x8 kb = *(const bf16x8*)&Km[(koff + nf * 16 + lr) * 40 + lk * 8];
        sc2[nf] = __builtin_amdgcn_mfma_f32_16x16x32_bf16(qa, kb,
                                                          f32x4{0.f,0.f,0.f,0.f}, 0, 0, 0);
      }
      float rmax2[4] = {-1e30f, -1e30f, -1e30f, -1e30f};
      float rsum2[4] = {0.f, 0.f, 0.f, 0.f};
      #pragma unroll
      for (int nf = 0; nf < 4; ++nf)
        #pragma unroll
        for (int r = 0; r < 4; ++r) {
          float v = sc2[nf][r] * scale;
          sc2[nf][r] = v;
          rmax2[r] = fmaxf(rmax2[r], v);
        }
      #pragma unroll
      for (int r = 0; r < 4; ++r) {
        float m = rmax2[r];
        #pragma unroll
        for (int d = 1; d < 16; d <<= 1) m = fmaxf(m, __shfl_xor(m, d, 64));
        rmax2[r] = m;
      }
      #pragma unroll
      for (int nf = 0; nf < 4; ++nf)
        #pragma unroll
        for (int r = 0; r < 4; ++r) {
          float p = __expf(sc2[nf][r] - rmax2[r]);
          rsum2[r] += p;
          P[(m0 + lk * 4 + r) * 136 + nf * 16 + lr] = f2bf(p);
        }
      float rs2[4];
      #pragma unroll
      for (int r = 0; r < 4; ++r) {
        float t = rsum2[r];
        #pragma unroll
        for (int d = 1; d < 16; d <<= 1) t += __shfl_xor(t, d, 64);
        rs2[r] = 1.f / t;
      }
      f32x4 oc[2];
      oc[0] = f32x4{0.f,0.f,0.f,0.f}; oc[1] = f32x4{0.f,0.f,0.f,0.f};
      #pragma unroll
      for (int kc = 0; kc < 2; ++kc) {
        bf16x8 pa = *(const bf16x8*)&P[(m0 + lr) * 136 + kc * 32 + lk * 8];
        #pragma unroll
        for (int nt = 0; nt < 2; ++nt) {
          bf16x8 vb = *(const bf16x8*)&VmT[(nt * 16 + lr) * 136 + koff + kc * 32 + lk * 8];
          oc[nt] = __builtin_amdgcn_mfma_f32_16x16x32_bf16(pa, vb, oc[nt], 0, 0, 0);
        }
      }
      #pragma unroll
      for (int nt = 0; nt < 2; ++nt)
        #pragma unroll
        for (int r = 0; r < 4; ++r) {
          size_t row = (size_t)b * 128 + m0 + lk * 4 + r;
          xcat[row * 512 + h * 32 + nt * 16 + lr] = f2bf(oc[nt][r] * rs2[r]);
        }
    }
  }
}

// ---------------- in-place projection GEMM ----------------
// out[262144][256] f32 = xcat[262144][512] bf16 @ Wpb[256][512]^T + bp.
// xcat and out alias (d_out). Block owns a 128-row tile: all xcat reads of
// those rows (global_load_lds, drained by the k-loop barriers) happen before
// the f32 epilogue overwrites the same bytes. Row-tiles are block-exclusive.

__global__ __launch_bounds__(512, 2) void proj_kernel(
    const unsigned short* __restrict__ xcat,
    const unsigned short* __restrict__ Wpb,
    const float* __restrict__ bp,
    float* __restrict__ out)
{
  __shared__ unsigned short Alds[2][128 * 64];     // 2 x 16 KB
  __shared__ unsigned short Blds[2][256 * 64];     // 2 x 32 KB

  const int tid = threadIdx.x, w = tid >> 6, lane = tid & 63;
  const int lr = lane & 15, lk = lane >> 4;
  const int wr = w >> 2, wc = w & 3;               // 2 x 4 wave grid
  const size_t m0 = (size_t)blockIdx.x * 128;

  f32x4 acc[4][4];
  #pragma unroll
  for (int i = 0; i < 4; ++i)
    #pragma unroll
    for (int j = 0; j < 4; ++j) acc[i][j] = f32x4{0.f, 0.f, 0.f, 0.f};

  auto stage = [&](int buf, int k0) {
    #pragma unroll
    for (int i = 0; i < 2; ++i) {                  // A: 128 x 64 bf16
      int L = (i * 512 + tid) * 16;
      int row = L >> 7;
      int inrow = (L & 127) ^ ((row & 7) << 4);
      gload_lds16((const char*)xcat + (m0 + row) * 1024 + k0 * 2 + inrow,
                  (char*)&Alds[buf][0] + L);
    }
    #pragma unroll
    for (int i = 0; i < 4; ++i) {                  // B: 256 x 64 bf16
      int L = (i * 512 + tid) * 16;
      int row = L >> 7;
      int inrow = (L & 127) ^ ((row & 7) << 4);
      gload_lds16((const char*)Wpb + (size_t)row * 1024 + k0 * 2 + inrow,
                  (char*)&Blds[buf][0] + L);
    }
  };

  stage(0, 0);
  __syncthreads();
  int cur = 0;
  for (int t = 0; t < 8; ++t) {
    if (t < 7) stage(cur ^ 1, (t + 1) * 64);
    const char* At = (const char*)&Alds[cur][0];
    const char* Bt = (const char*)&Blds[cur][0];
    #pragma unroll
    for (int kk = 0; kk < 2; ++kk) {
      bf16x8 af[4], bfr[4];
      #pragma unroll
      for (int mt = 0; mt < 4; ++mt) {
        int row = wr * 64 + mt * 16 + lr;
        int off = (row * 128 + kk * 64 + lk * 16) ^ ((row & 7) << 4);
        af[mt] = *(const bf16x8*)(At + off);
      }
      #pragma unroll
      for (int nt = 0; nt < 4; ++nt) {
        int row = wc * 64 + nt * 16 + lr;
        int off = (row * 128 + kk * 64 + lk * 16) ^ ((row & 7) << 4);
        bfr[nt] = *(const bf16x8*)(Bt + off);
      }
      #pragma unroll
      for (int mt = 0; mt < 4; ++mt)
        #pragma unroll
        for (int nt = 0; nt < 4; ++nt)
          acc[mt][nt] = __builtin_amdgcn_mfma_f32_16x16x32_bf16(af[mt], bfr[nt],
                                                                acc[mt][nt], 0, 0, 0);
    }
    __syncthreads();
    cur ^= 1;
  }

  #pragma unroll
  for (int mt = 0; mt < 4; ++mt)
    #pragma unroll
    for (int r = 0; r < 4; ++r) {
      size_t grow = m0 + wr * 64 + mt * 16 + lk * 4 + r;
      #pragma unroll
      for (int nt = 0; nt < 4; ++nt) {
        int gcol = wc * 64 + nt * 16 + lr;
        out[grow * 256 + gcol] = acc[mt][nt][r] + bp[gcol];
      }
    }
}

// ---------------- launch ----------------

extern "C" void kernel_launch(void* const* d_in, const int* in_sizes, int n_in,
                              void* d_out, int out_size, void* d_ws, size_t ws_size,
                              hipStream_t stream) {
  (void)in_sizes; (void)n_in; (void)out_size;
  const float* x   = (const float*)d_in[0];
  const float* rpb = (const float*)d_in[1];
  const float* Wqs = (const float*)d_in[2];
  const float* Wqm = (const float*)d_in[3];
  const float* Wp  = (const float*)d_in[4];
  const float* bp  = (const float*)d_in[5];
  char* ws = (char*)d_ws;

  // workspace: tables only (2,097,152 bytes)
  size_t off = 0;
  float* pos_t  = (float*)(ws + off); off += 32768ull  * 4;
  float* posW   = (float*)(ws + off); off += 98304ull  * 4;
  float* bias_t = (float*)(ws + off); off += 131072ull * 4;
  unsigned short* Wsb = (unsigned short*)(ws + off); off += 196608ull * 2;
  unsigned short* Wmb = (unsigned short*)(ws + off); off += 196608ull * 2;
  unsigned short* Wpb = (unsigned short*)(ws + off); off += 131072ull * 2;
  if (ws_size < off) return;                        // 2 MB — should always fit

  // xcat (bf16 [262144][512] = 268,435,456 B) lives in d_out (same size);
  // proj_kernel then runs in-place.
  unsigned short* xcat = (unsigned short*)d_out;

  pos_kernel <<<dim3(128),  dim3(256), 0, stream>>>(pos_t);
  bias_kernel<<<dim3(512),  dim3(256), 0, stream>>>(rpb, bias_t);
  wconv_kernel<<<dim3(2048), dim3(256), 0, stream>>>(Wqs, Wqm, Wp, Wsb, Wmb, Wpb);
  posw_kernel<<<dim3(384),  dim3(256), 0, stream>>>(pos_t, Wqm, posW);

  fused_attn<<<dim3(2048), dim3(512), 0, stream>>>(x, Wsb, Wmb, posW, bias_t, xcat);

  proj_kernel<<<dim3(2048), dim3(512), 0, stream>>>(xcat, Wpb, bp, (float*)d_out);
}

// Round 3
// 1237.706 us; speedup vs baseline: 1.5024x; 1.5024x over previous
//
#include <hip/hip_runtime.h>

// ---------------------------------------------------------------------------
// WindowAttention fused pipeline for MI355X (gfx950)
//   B=2048 windows, N=128 tokens, C=256, H=8 heads, hd=32
// Round-3 structure: per-(window,head) blocks (16384), 512 thr, 78.8KB LDS
// -> 2 blocks/CU (4 waves/SIMD). x streamed via 16KB LDS slab dbuf.
// xcat (bf16) lives in d_out; proj GEMM runs in-place (proven round-2 path).
// ---------------------------------------------------------------------------

typedef __attribute__((ext_vector_type(8))) short     short8;
typedef __attribute__((ext_vector_type(8))) __bf16    bf16x8;
typedef __attribute__((ext_vector_type(4))) float     f32x4;

__device__ __forceinline__ unsigned short f2bf(float f) {
  unsigned int u = __float_as_uint(f);
  u = (u + 0x7fffu + ((u >> 16) & 1u)) >> 16;
  return (unsigned short)u;
}

__device__ __forceinline__ void gload_lds16(const void* g, void* l) {
  __builtin_amdgcn_global_load_lds((const __attribute__((address_space(1))) void*)g,
                                   (__attribute__((address_space(3))) void*)l, 16, 0, 0);
}

// ---------------- precompute kernels (~2 MB of ws) ----------------

__global__ void pos_kernel(float* __restrict__ pos_t) {
  int e = blockIdx.x * 256 + threadIdx.x;          // 32768 = 128*256
  int t = e >> 8, c = e & 255;
  int p = t & 63;                                   // tiled (1,2,1)
  const float norm = 6.28318530717958647692f / 8.000001f;  // scale/(8+1e-6)
  float yn = (float)((p >> 3) + 1) * norm;
  float xn = (float)((p & 7) + 1) * norm;
  int cc = c & 127;
  int m  = cc >> 1;
  float v = ((c < 128) ? yn : xn) * __expf(-(float)m * 0.14391156831f);
  pos_t[e] = (cc & 1) ? cosf(v) : sinf(v);
}

__global__ void posw_kernel(const float* __restrict__ pos_t,
                            const float* __restrict__ Wm,
                            float* __restrict__ posW) {
  int e = blockIdx.x * 256 + threadIdx.x;          // 98304 = 128*768
  int t = e / 768, c = e - t * 768;
  const float4* pr = (const float4*)(pos_t + t * 256);
  const float4* wr = (const float4*)(Wm + (size_t)c * 256);
  float acc = 0.f;
  #pragma unroll 8
  for (int k = 0; k < 64; ++k) {
    float4 p = pr[k], w = wr[k];
    acc += p.x * w.x + p.y * w.y + p.z * w.z + p.w * w.w;
  }
  posW[e] = acc;
}

__global__ void bias_kernel(const float* __restrict__ rpb, float* __restrict__ bias_t) {
  int e = blockIdx.x * 256 + threadIdx.x;          // 131072 = 8*128*128
  int h = e >> 14, i = (e >> 7) & 127, j = e & 127;
  int di = i >> 6, hi = (i >> 3) & 7, wi = i & 7;
  int dj = j >> 6, hj = (j >> 3) & 7, wj = j & 7;
  int idx = (di - dj + 1) * 225 + (hi - hj + 7) * 15 + (wi - wj + 7);
  bias_t[e] = rpb[idx * 8 + h];
}

__global__ void wconv_kernel(const float* __restrict__ Ws, const float* __restrict__ Wm,
                             const float* __restrict__ Wp,
                             unsigned short* __restrict__ Wsb,
                             unsigned short* __restrict__ Wmb,
                             unsigned short* __restrict__ Wpb) {
  int e = blockIdx.x * 256 + threadIdx.x;          // 524288
  if (e < 196608)       Wsb[e]          = f2bf(Ws[e]);
  else if (e < 393216)  Wmb[e - 196608] = f2bf(Wm[e - 196608]);
  else                  Wpb[e - 393216] = f2bf(Wp[e - 393216]);
}

// ---------------- fused per-(window,head) QKV + attention ----------------
// 8 waves. Phase A: QKV head GEMM (x via LDS slab dbuf, W from L2).
// Phase B: self attention (+bias, 128 keys). Phase C: mutual half-swap (64).
// Wave roles: Phase A: mh=(w>>2)*64 rows, 3 of 12 (o,nt) col-units.
//             Phase B/C: 16-row output strip m0=w*16 (P rows wave-private).

__global__ __launch_bounds__(512, 4) void fused_head(
    const float* __restrict__ x,
    const unsigned short* __restrict__ Wsb,
    const unsigned short* __restrict__ Wmb,
    const float* __restrict__ posW,
    const float* __restrict__ bias_t,
    unsigned short* __restrict__ xcat)
{
  __shared__ unsigned short Qs[128 * 40];          // 10240 B, stride 80B (16B mult)
  __shared__ unsigned short Ks[128 * 40];
  __shared__ unsigned short Qm[128 * 40];
  __shared__ unsigned short Km[128 * 40];
  __shared__ unsigned short VsT[32 * 136];         // 8704 B, [d][token], stride 272B
  __shared__ unsigned short VmT[32 * 136];
  __shared__ unsigned short PX[2 * 128 * 40];      // Phase A: x-slab dbuf; B/C: P

  // bijective swizzle: XCD = blockIdx%8 = b%8 -> 8 windows x 8 heads per XCD
  const int kblk = blockIdx.x;
  const int b = (kblk & 7) | ((kblk >> 6) << 3);
  const int h = (kblk >> 3) & 7;

  const int tid = threadIdx.x, w = tid >> 6, lane = tid & 63;
  const int lr = lane & 15, lk = lane >> 4;
  const float scale = 0.17677669529663688f;        // 32^-0.5
  const float* xb = x + (size_t)b * 32768;

  // ======== Phase A: QKV for head h ========
  const int mh = (w >> 2) * 64;
  const int u0 = (w & 3) * 3;
  f32x4 acc[3][4];
  #pragma unroll
  for (int i = 0; i < 3; ++i)
    #pragma unroll
    for (int mt = 0; mt < 4; ++mt) acc[i][mt] = f32x4{0.f, 0.f, 0.f, 0.f};

  int uo[3], unt[3];
  const unsigned short* wbase[3];
  #pragma unroll
  for (int i = 0; i < 3; ++i) {
    int u = u0 + i;
    int o = u >> 1, nt = u & 1;
    uo[i] = o; unt[i] = nt;
    int o3 = (o < 3) ? o : o - 3;
    wbase[i] = ((o < 3) ? Wsb : Wmb)
             + (size_t)(o3 * 256 + h * 32 + nt * 16 + lr) * 256 + lk * 8;
  }

  // stage x slab [128 rows][32 cols] f32 -> bf16 into PX[buf]
  const int srow = tid >> 2, sc8 = (tid & 3) * 8;
  auto stage = [&](int buf, int kc) {
    const float* src = xb + srow * 256 + kc * 32 + sc8;
    float4 a = *(const float4*)src, d = *(const float4*)(src + 4);
    short8 o8;
    o8[0] = (short)f2bf(a.x); o8[1] = (short)f2bf(a.y);
    o8[2] = (short)f2bf(a.z); o8[3] = (short)f2bf(a.w);
    o8[4] = (short)f2bf(d.x); o8[5] = (short)f2bf(d.y);
    o8[6] = (short)f2bf(d.z); o8[7] = (short)f2bf(d.w);
    *(short8*)&PX[buf * 5120 + srow * 40 + sc8] = o8;
  };

  stage(0, 0);
  __syncthreads();
  int cur = 0;
  #pragma unroll
  for (int kc = 0; kc < 8; ++kc) {
    if (kc < 7) stage(cur ^ 1, kc + 1);
    bf16x8 af[4];
    #pragma unroll
    for (int mt = 0; mt < 4; ++mt)
      af[mt] = *(const bf16x8*)&PX[cur * 5120 + (mh + mt * 16 + lr) * 40 + lk * 8];
    #pragma unroll
    for (int i = 0; i < 3; ++i) {
      bf16x8 wf = *(const bf16x8*)(wbase[i] + kc * 32);
      #pragma unroll
      for (int mt = 0; mt < 4; ++mt)
        acc[i][mt] = __builtin_amdgcn_mfma_f32_16x16x32_bf16(af[mt], wf,
                                                             acc[i][mt], 0, 0, 0);
    }
    __syncthreads();
    cur ^= 1;
  }

  // epilogue: C layout row=(lane>>4)*4+r, col=lane&15
  #pragma unroll
  for (int i = 0; i < 3; ++i) {
    int o = uo[i], nt = unt[i];
    #pragma unroll
    for (int mt = 0; mt < 4; ++mt)
      #pragma unroll
      for (int r = 0; r < 4; ++r) {
        int row  = mh + mt * 16 + lk * 4 + r;       // token
        int dcol = nt * 16 + lr;                    // d within 32
        float v = acc[i][mt][r];
        if (o >= 3) v += posW[row * 768 + (o - 3) * 256 + h * 32 + dcol];
        if (o == 2)      VsT[dcol * 136 + row] = f2bf(v);
        else if (o == 5) VmT[dcol * 136 + row] = f2bf(v);
        else {
          unsigned short* Qb = (o == 0) ? Qs : (o == 1) ? Ks : (o == 3) ? Qm : Km;
          Qb[row * 40 + dcol] = f2bf(v);
        }
      }
  }
  __syncthreads();   // QKV visible; PX free for P use (all slab reads done)

  unsigned short* P = PX;                           // [128][40], 32-key chunks
  const int m0 = w * 16;

  // ======== Phase B: self attention (128 keys, +bias) ========
  {
    f32x4 sc[8];
    bf16x8 qa = *(const bf16x8*)&Qs[(m0 + lr) * 40 + lk * 8];
    #pragma unroll
    for (int nf = 0; nf < 8; ++nf) {
      bf16x8 kb = *(const bf16x8*)&Ks[(nf * 16 + lr) * 40 + lk * 8];
      sc[nf] = __builtin_amdgcn_mfma_f32_16x16x32_bf16(qa, kb,
                                                       f32x4{0.f,0.f,0.f,0.f}, 0, 0, 0);
    }
    const float* bt = bias_t + (size_t)h * 16384 + (m0 + lk * 4) * 128;
    float rmax[4] = {-1e30f, -1e30f, -1e30f, -1e30f};
    float rsum[4] = {0.f, 0.f, 0.f, 0.f};
    #pragma unroll
    for (int nf = 0; nf < 8; ++nf)
      #pragma unroll
      for (int r = 0; r < 4; ++r) {
        float v = sc[nf][r] * scale + bt[r * 128 + nf * 16 + lr];
        sc[nf][r] = v;
        rmax[r] = fmaxf(rmax[r], v);
      }
    #pragma unroll
    for (int r = 0; r < 4; ++r) {
      float m = rmax[r];
      #pragma unroll
      for (int d = 1; d < 16; d <<= 1) m = fmaxf(m, __shfl_xor(m, d, 64));
      rmax[r] = m;
    }
    #pragma unroll
    for (int nf = 0; nf < 8; ++nf)
      #pragma unroll
      for (int r = 0; r < 4; ++r) {
        float p = __expf(sc[nf][r] - rmax[r]);
        rsum[r] += p;
        sc[nf][r] = p;
      }
    float rs[4];
    #pragma unroll
    for (int r = 0; r < 4; ++r) {
      float t = rsum[r];
      #pragma unroll
      for (int d = 1; d < 16; d <<= 1) t += __shfl_xor(t, d, 64);
      rs[r] = 1.f / t;
    }
    // PV in 32-key chunks (P rows wave-private; same-wave ds order via lgkmcnt)
    f32x4 oc[2];
    oc[0] = f32x4{0.f,0.f,0.f,0.f}; oc[1] = f32x4{0.f,0.f,0.f,0.f};
    #pragma unroll
    for (int c = 0; c < 4; ++c) {
      #pragma unroll
      for (int nf2 = 0; nf2 < 2; ++nf2)
        #pragma unroll
        for (int r = 0; r < 4; ++r)
          P[(m0 + lk * 4 + r) * 40 + nf2 * 16 + lr] = f2bf(sc[c * 2 + nf2][r]);
      bf16x8 pa = *(const bf16x8*)&P[(m0 + lr) * 40 + lk * 8];
      #pragma unroll
      for (int nt = 0; nt < 2; ++nt) {
        bf16x8 vb = *(const bf16x8*)&VsT[(nt * 16 + lr) * 136 + c * 32 + lk * 8];
        oc[nt] = __builtin_amdgcn_mfma_f32_16x16x32_bf16(pa, vb, oc[nt], 0, 0, 0);
      }
    }
    #pragma unroll
    for (int nt = 0; nt < 2; ++nt)
      #pragma unroll
      for (int r = 0; r < 4; ++r) {
        size_t row = (size_t)b * 128 + m0 + lk * 4 + r;
        xcat[row * 512 + 256 + h * 32 + nt * 16 + lr] = f2bf(oc[nt][r] * rs[r]);
      }
  }

  // ======== Phase C: mutual attention (half swap, 64 keys, no bias) ========
  {
    const int q0   = (w < 4) ? 64 + m0 : m0 - 64;  // out rows 0..63 use q2; 64..127 q1
    const int koff = (w < 4) ? 0 : 64;             // k1/v1 vs k2/v2
    f32x4 sc2[4];
    bf16x8 qa = *(const bf16x8*)&Qm[(q0 + lr) * 40 + lk * 8];
    #pragma unroll
    for (int nf = 0; nf < 4; ++nf) {
      bf16x8 kb = *(const bf16x8*)&Km[(koff + nf * 16 + lr) * 40 + lk * 8];
      sc2[nf] = __builtin_amdgcn_mfma_f32_16x16x32_bf16(qa, kb,
                                                        f32x4{0.f,0.f,0.f,0.f}, 0, 0, 0);
    }
    float rmax2[4] = {-1e30f, -1e30f, -1e30f, -1e30f};
    float rsum2[4] = {0.f, 0.f, 0.f, 0.f};
    #pragma unroll
    for (int nf = 0; nf < 4; ++nf)
      #pragma unroll
      for (int r = 0; r < 4; ++r) {
        float v = sc2[nf][r] * scale;
        sc2[nf][r] = v;
        rmax2[r] = fmaxf(rmax2[r], v);
      }
    #pragma unroll
    for (int r = 0; r < 4; ++r) {
      float m = rmax2[r];
      #pragma unroll
      for (int d = 1; d < 16; d <<= 1) m = fmaxf(m, __shfl_xor(m, d, 64));
      rmax2[r] = m;
    }
    #pragma unroll
    for (int nf = 0; nf < 4; ++nf)
      #pragma unroll
      for (int r = 0; r < 4; ++r) {
        float p = __expf(sc2[nf][r] - rmax2[r]);
        rsum2[r] += p;
        sc2[nf][r] = p;
      }
    float rs2[4];
    #pragma unroll
    for (int r = 0; r < 4; ++r) {
      float t = rsum2[r];
      #pragma unroll
      for (int d = 1; d < 16; d <<= 1) t += __shfl_xor(t, d, 64);
      rs2[r] = 1.f / t;
    }
    f32x4 oc[2];
    oc[0] = f32x4{0.f,0.f,0.f,0.f}; oc[1] = f32x4{0.f,0.f,0.f,0.f};
    #pragma unroll
    for (int c = 0; c < 2; ++c) {
      #pragma unroll
      for (int nf2 = 0; nf2 < 2; ++nf2)
        #pragma unroll
        for (int r = 0; r < 4; ++r)
          P[(m0 + lk * 4 + r) * 40 + nf2 * 16 + lr] = f2bf(sc2[c * 2 + nf2][r]);
      bf16x8 pa = *(const bf16x8*)&P[(m0 + lr) * 40 + lk * 8];
      #pragma unroll
      for (int nt = 0; nt < 2; ++nt) {
        bf16x8 vb = *(const bf16x8*)&VmT[(nt * 16 + lr) * 136 + koff + c * 32 + lk * 8];
        oc[nt] = __builtin_amdgcn_mfma_f32_16x16x32_bf16(pa, vb, oc[nt], 0, 0, 0);
      }
    }
    #pragma unroll
    for (int nt = 0; nt < 2; ++nt)
      #pragma unroll
      for (int r = 0; r < 4; ++r) {
        size_t row = (size_t)b * 128 + m0 + lk * 4 + r;
        xcat[row * 512 + h * 32 + nt * 16 + lr] = f2bf(oc[nt][r] * rs2[r]);
      }
  }
}

// ---------------- in-place projection GEMM (unchanged, proven) ----------------
// out[262144][256] f32 = xcat[262144][512] bf16 @ Wpb[256][512]^T + bp.
// xcat and out alias (d_out); row-tiles are block-exclusive.

__global__ __launch_bounds__(512, 2) void proj_kernel(
    const unsigned short* __restrict__ xcat,
    const unsigned short* __restrict__ Wpb,
    const float* __restrict__ bp,
    float* __restrict__ out)
{
  __shared__ unsigned short Alds[2][128 * 64];     // 2 x 16 KB
  __shared__ unsigned short Blds[2][256 * 64];     // 2 x 32 KB

  const int tid = threadIdx.x, w = tid >> 6, lane = tid & 63;
  const int lr = lane & 15, lk = lane >> 4;
  const int wr = w >> 2, wc = w & 3;               // 2 x 4 wave grid
  const size_t m0 = (size_t)blockIdx.x * 128;

  f32x4 acc[4][4];
  #pragma unroll
  for (int i = 0; i < 4; ++i)
    #pragma unroll
    for (int j = 0; j < 4; ++j) acc[i][j] = f32x4{0.f, 0.f, 0.f, 0.f};

  auto stage = [&](int buf, int k0) {
    #pragma unroll
    for (int i = 0; i < 2; ++i) {                  // A: 128 x 64 bf16
      int L = (i * 512 + tid) * 16;
      int row = L >> 7;
      int inrow = (L & 127) ^ ((row & 7) << 4);
      gload_lds16((const char*)xcat + (m0 + row) * 1024 + k0 * 2 + inrow,
                  (char*)&Alds[buf][0] + L);
    }
    #pragma unroll
    for (int i = 0; i < 4; ++i) {                  // B: 256 x 64 bf16
      int L = (i * 512 + tid) * 16;
      int row = L >> 7;
      int inrow = (L & 127) ^ ((row & 7) << 4);
      gload_lds16((const char*)Wpb + (size_t)row * 1024 + k0 * 2 + inrow,
                  (char*)&Blds[buf][0] + L);
    }
  };

  stage(0, 0);
  __syncthreads();
  int cur = 0;
  for (int t = 0; t < 8; ++t) {
    if (t < 7) stage(cur ^ 1, (t + 1) * 64);
    const char* At = (const char*)&Alds[cur][0];
    const char* Bt = (const char*)&Blds[cur][0];
    #pragma unroll
    for (int kk = 0; kk < 2; ++kk) {
      bf16x8 af[4], bfr[4];
      #pragma unroll
      for (int mt = 0; mt < 4; ++mt) {
        int row = wr * 64 + mt * 16 + lr;
        int off = (row * 128 + kk * 64 + lk * 16) ^ ((row & 7) << 4);
        af[mt] = *(const bf16x8*)(At + off);
      }
      #pragma unroll
      for (int nt = 0; nt < 4; ++nt) {
        int row = wc * 64 + nt * 16 + lr;
        int off = (row * 128 + kk * 64 + lk * 16) ^ ((row & 7) << 4);
        bfr[nt] = *(const bf16x8*)(Bt + off);
      }
      #pragma unroll
      for (int mt = 0; mt < 4; ++mt)
        #pragma unroll
        for (int nt = 0; nt < 4; ++nt)
          acc[mt][nt] = __builtin_amdgcn_mfma_f32_16x16x32_bf16(af[mt], bfr[nt],
                                                                acc[mt][nt], 0, 0, 0);
    }
    __syncthreads();
    cur ^= 1;
  }

  #pragma unroll
  for (int mt = 0; mt < 4; ++mt)
    #pragma unroll
    for (int r = 0; r < 4; ++r) {
      size_t grow = m0 + wr * 64 + mt * 16 + lk * 4 + r;
      #pragma unroll
      for (int nt = 0; nt < 4; ++nt) {
        int gcol = wc * 64 + nt * 16 + lr;
        out[grow * 256 + gcol] = acc[mt][nt][r] + bp[gcol];
      }
    }
}

// ---------------- launch ----------------

extern "C" void kernel_launch(void* const* d_in, const int* in_sizes, int n_in,
                              void* d_out, int out_size, void* d_ws, size_t ws_size,
                              hipStream_t stream) {
  (void)in_sizes; (void)n_in; (void)out_size;
  const float* x   = (const float*)d_in[0];
  const float* rpb = (const float*)d_in[1];
  const float* Wqs = (const float*)d_in[2];
  const float* Wqm = (const float*)d_in[3];
  const float* Wp  = (const float*)d_in[4];
  const float* bp  = (const float*)d_in[5];
  char* ws = (char*)d_ws;

  // workspace: tables only (2,097,152 bytes)
  size_t off = 0;
  float* pos_t  = (float*)(ws + off); off += 32768ull  * 4;
  float* posW   = (float*)(ws + off); off += 98304ull  * 4;
  float* bias_t = (float*)(ws + off); off += 131072ull * 4;
  unsigned short* Wsb = (unsigned short*)(ws + off); off += 196608ull * 2;
  unsigned short* Wmb = (unsigned short*)(ws + off); off += 196608ull * 2;
  unsigned short* Wpb = (unsigned short*)(ws + off); off += 131072ull * 2;
  if (ws_size < off) return;                        // 2 MB — should always fit

  // xcat (bf16 [262144][512] = 268,435,456 B) lives in d_out; proj runs in-place.
  unsigned short* xcat = (unsigned short*)d_out;

  pos_kernel <<<dim3(128),  dim3(256), 0, stream>>>(pos_t);
  bias_kernel<<<dim3(512),  dim3(256), 0, stream>>>(rpb, bias_t);
  wconv_kernel<<<dim3(2048), dim3(256), 0, stream>>>(Wqs, Wqm, Wp, Wsb, Wmb, Wpb);
  posw_kernel<<<dim3(384),  dim3(256), 0, stream>>>(pos_t, Wqm, posW);

  fused_head<<<dim3(16384), dim3(512), 0, stream>>>(x, Wsb, Wmb, posW, bias_t, xcat);

  proj_kernel<<<dim3(2048), dim3(512), 0, stream>>>(xcat, Wpb, bp, (float*)d_out);
}